// Round 7
// baseline (391.037 us; speedup 1.0000x reference)
//
#include <hip/hip_runtime.h>
#include <hip/hip_bf16.h>
#include <math.h>
#include <stdint.h>

#define B_     32
#define HH_    28
#define WW_    28
#define N_     784
#define C_     384
#define M_     25088      // B_*N_
#define HEADS_ 8
#define HD_    48
#define HID_   1536

typedef __bf16 bf16;
typedef __attribute__((ext_vector_type(8))) __bf16 bf16x8;
typedef __attribute__((ext_vector_type(4))) __bf16 bf16x4;
typedef __attribute__((ext_vector_type(4))) float f32x4;

// async global->LDS, 16B per lane; LDS dest = wave-uniform base + lane*16
__device__ __forceinline__ void gload_lds16(const void* g, void* l) {
    __builtin_amdgcn_global_load_lds(
        (const __attribute__((address_space(1))) unsigned int*)g,
        (__attribute__((address_space(3))) unsigned int*)(uintptr_t)l,
        16, 0, 0);
}

// fast GELU: v*sigmoid(2u), u = 0.79788456(v+0.044715v^3); validated R8-R13:
// absmax identical (0.03125) to erff baseline under bf16 rounding.
__device__ __forceinline__ float gelu_f(float v) {
    float u = 0.7978845608028654f * v * (1.f + 0.044715f * v * v);
    return __fdividef(v, 1.f + __expf(-2.f * u));
}

// ------- weights fp32 -> bf16 (4 tensors) + CPE weight transpose, one launch -------
__global__ void prep_kernel(const float* __restrict__ a, int na,
                            const float* __restrict__ b, int nb,
                            const float* __restrict__ c, int nc,
                            const float* __restrict__ d, int nd,
                            bf16* __restrict__ out,
                            const float* __restrict__ w0, const float* __restrict__ w1,
                            float* __restrict__ wt0, float* __restrict__ wt1) {
    int i = blockIdx.x * 256 + threadIdx.x;
    const int tot = na + nb + nc + nd;
    if (i < tot) {
        int j = i;
        const float* src;
        if (j < na) src = a + j;
        else { j -= na;
            if (j < nb) src = b + j;
            else { j -= nb;
                if (j < nc) src = c + j;
                else { j -= nc; src = d + j; } } }
        out[i] = (bf16)(*src);
    } else {
        int k = i - tot;                 // 0..C_*9-1
        if (k < C_ * 9) {
            int cc = k / 9, tt = k - cc * 9;
            wt0[tt * C_ + cc] = w0[k];
            wt1[tt * C_ + cc] = w1[k];
        }
    }
}

// ------- depthwise 3x3 conv + bias + residual, fused LayerNorm -> bf16 -------
// ONE WAVE PER ROW: lane l owns channels {l, l+64, ..., l+320}. LN reduction is a
// pure __shfl_xor butterfly — zero barriers, zero LDS. Border branch is
// wave-uniform (py/px per-row). Interior: 48 independent coalesced dword loads
// in flight. XCD-chunk swizzle: block f -> rows (f%8)*3136 + (f>>3)*4, so each
// XCD works on 4 whole images -> vertical 3x3 re-reads hit its own L2.
__global__ __launch_bounds__(256)
void cpe_ln_kernel(const float* __restrict__ x, const float* __restrict__ wt,
                   const float* __restrict__ bias, float* __restrict__ y,
                   const float* __restrict__ g, const float* __restrict__ beta,
                   bf16* __restrict__ lnout) {
    const int wave = threadIdx.x >> 6, lane = threadIdx.x & 63;
    const int f = blockIdx.x;
    const int row = (f & 7) * 3136 + (f >> 3) * 4 + wave;   // bijective over M_
    const int b = row / N_;
    const int n = row - b * N_;
    const int py = n / WW_, px = n - py * WW_;

    float acc[6], ctr[6];
    const float* xrow = x + (size_t)row * C_ + lane;
    #pragma unroll
    for (int j = 0; j < 6; j++) {
        acc[j] = bias[lane + j * 64];
        ctr[j] = xrow[j * 64];
    }

    if (py >= 1 && py <= 26 && px >= 1 && px <= 26) {
        // interior: 8 taps loaded unconditionally (center reuses ctr)
        const float* p = x + (size_t)(row - WW_ - 1) * C_ + lane;
        float v[9][6];
        #pragma unroll
        for (int t = 0; t < 9; t++) {
            if (t == 4) continue;
            const float* pt = p + ((t / 3) * WW_ + (t % 3)) * C_;
            #pragma unroll
            for (int j = 0; j < 6; j++) v[t][j] = pt[j * 64];
        }
        #pragma unroll
        for (int t = 0; t < 9; t++) {
            #pragma unroll
            for (int j = 0; j < 6; j++) {
                float xv = (t == 4) ? ctr[j] : v[t][j];
                acc[j] += wt[t * C_ + lane + j * 64] * xv;
            }
        }
    } else {
        #pragma unroll
        for (int t = 0; t < 9; t++) {
            int yy = py + t / 3 - 1, xx = px + t % 3 - 1;
            if (yy < 0 || yy >= HH_ || xx < 0 || xx >= WW_) continue;
            const float* pt = x + (size_t)(b * N_ + yy * WW_ + xx) * C_ + lane;
            #pragma unroll
            for (int j = 0; j < 6; j++)
                acc[j] += wt[t * C_ + lane + j * 64] * pt[j * 64];
        }
    }
    #pragma unroll
    for (int j = 0; j < 6; j++) acc[j] += ctr[j];

    float* yrow = y + (size_t)row * C_ + lane;
    #pragma unroll
    for (int j = 0; j < 6; j++) yrow[j * 64] = acc[j];

    // ---- LN: wave-wide butterfly, no barriers ----
    float s = 0.f;
    #pragma unroll
    for (int j = 0; j < 6; j++) s += acc[j];
    #pragma unroll
    for (int off = 1; off < 64; off <<= 1) s += __shfl_xor(s, off, 64);
    float mean = s * (1.f / C_);
    float d[6], vs = 0.f;
    #pragma unroll
    for (int j = 0; j < 6; j++) { d[j] = acc[j] - mean; vs += d[j] * d[j]; }
    #pragma unroll
    for (int off = 1; off < 64; off <<= 1) vs += __shfl_xor(vs, off, 64);
    float rstd = rsqrtf(vs * (1.f / C_) + 1e-5f);
    bf16* lrow = lnout + (size_t)row * C_ + lane;
    #pragma unroll
    for (int j = 0; j < 6; j++) {
        int c = lane + j * 64;
        lrow[j * 64] = (bf16)(d[j] * rstd * g[c] + beta[c]);
    }
}

// -------- bf16 MFMA GEMM: ring-2 (32KB LDS -> 5 blocks/CU), 1 barrier/iter --------
// R14: only the ring depth changes vs R13 (the verified 372.98us best).
// Evidence R7-R12 is monotone in blocks/CU (3->67.9 | 2->70.5 | ~1.5->65 | 1->75-108):
// the per-iter barrier+drain stall is hidden ONLY by other co-resident blocks
// (m114 mechanism; in-block waves cannot cross a barrier). Ring-3->ring-2 shrinks
// LDS 48->32KB: 5 blocks/CU = 20 waves/CU. Cost: prefetch dist 2->1, wait becomes
// vmcnt(0) — but the waited tile was issued a full iteration (~2.7k wall cycles,
// mostly L2/L3-hit latency) earlier, so added in-block stall is small vs 5-way
// cross-block hiding. Race-safe: at iter-s barrier every wave finished iter s-1's
// LDS reads (lgkmcnt precedes MFMA), so writing buffer (s+1)&1 is safe; vmcnt(0)
// precedes the issue so it only drains tile s.
// Keeps: gelu_f, XOR-swizzle pair (conflicts 0), scalar epilogue (beat vec by
// 3.5us at VGPR 68 — R11), XCD block-grouping.
template<bool BIAS, bool GELU, bool RESID, bool OUTBF>
__global__ __launch_bounds__(256)
void gemm_kernel(const bf16* __restrict__ A, const bf16* __restrict__ Wt,
                 const float* __restrict__ bias, const float* __restrict__ resid,
                 void* __restrict__ outp, int M, int N, int K) {
    __shared__ __align__(16) bf16 As[2 * 4096];
    __shared__ __align__(16) bf16 Bs[2 * 4096];

    const int nbn = gridDim.x, nbm = gridDim.y;
    const int f = blockIdx.y * nbn + blockIdx.x;
    const int grp = f / (8 * nbn);
    const int rem = f - grp * 8 * nbn;
    const int rows = min(8, nbm - grp * 8);
    const int bm = (grp * 8 + rem % rows) * 128;
    const int bn = (rem / rows) * 128;

    const int t = threadIdx.x;
    const int wave = t >> 6, lane = t & 63;
    const int wm = (wave & 1) * 64, wn = (wave >> 1) * 64;
    const int quad = lane >> 4, r = lane & 15;

    const int ldrow = lane >> 2;
    // inverse swizzle on the global source: col-slot ^= row[2:1] (row_local = lane>>2)
    const int ldcol = ((lane & 3) ^ ((lane >> 3) & 3)) * 8;
    const bf16* ga0 = A  + (size_t)(bm + wave * 32 + ldrow) * K + ldcol;
    const bf16* ga1 = ga0 + (size_t)16 * K;
    const bf16* gb0 = Wt + (size_t)(bn + wave * 32 + ldrow) * K + ldcol;
    const bf16* gb1 = gb0 + (size_t)16 * K;
    const int lbase = wave * 32 * 32;
    const int nk = K >> 5;

    auto issue = [&](int st) {
        const int bb = (st & 1) * 4096;
        const int kk = st * 32;
        gload_lds16(ga0 + kk, &As[bb + lbase]);
        gload_lds16(ga1 + kk, &As[bb + lbase + 512]);
        gload_lds16(gb0 + kk, &Bs[bb + lbase]);
        gload_lds16(gb1 + kk, &Bs[bb + lbase + 512]);
    };

    f32x4 acc[4][4] = {};
    issue(0);

    // read-side swizzle: col-quad ^= r[2:1] (row bits beyond r are multiples of 16)
    const int sq = (quad ^ ((r >> 1) & 3)) * 8;

    for (int s = 0; s < nk; ++s) {
        asm volatile("s_waitcnt vmcnt(0)" ::: "memory");
        asm volatile("s_barrier" ::: "memory");
        if (s + 1 < nk) issue(s + 1);

        const bf16* as = &As[(s & 1) * 4096];
        const bf16* bs = &Bs[(s & 1) * 4096];
        bf16x8 af[4], bfr[4];
        #pragma unroll
        for (int i = 0; i < 4; i++)
            af[i] = *(const bf16x8*)(&as[(wm + i * 16 + r) * 32 + sq]);
        #pragma unroll
        for (int j = 0; j < 4; j++)
            bfr[j] = *(const bf16x8*)(&bs[(wn + j * 16 + r) * 32 + sq]);
        #pragma unroll
        for (int i = 0; i < 4; i++)
            #pragma unroll
            for (int j = 0; j < 4; j++)
                acc[i][j] = __builtin_amdgcn_mfma_f32_16x16x32_bf16(af[i], bfr[j], acc[i][j], 0, 0, 0);
    }

    #pragma unroll
    for (int i = 0; i < 4; i++) {
        #pragma unroll
        for (int j = 0; j < 4; j++) {
            int n = bn + wn + j * 16 + r;
            float bv = BIAS ? bias[n] : 0.f;
            #pragma unroll
            for (int e = 0; e < 4; e++) {
                int m = bm + wm + i * 16 + quad * 4 + e;
                float val = acc[i][j][e] + bv;
                if (GELU) val = gelu_f(val);
                if (RESID) val += resid[(size_t)m * N + n];
                if (OUTBF) ((bf16*)outp)[(size_t)m * N + n] = (bf16)val;
                else       ((float*)outp)[(size_t)m * N + n] = val;
            }
        }
    }
}

// ---------------- fused channel attention (scores + softmax + apply), MFMA ----------
__global__ __launch_bounds__(256)
void attn_fused_kernel(const bf16* __restrict__ qkvb, bf16* __restrict__ outp) {
    __shared__ __align__(16) bf16 stage[4][3872];
    __shared__ float Sred[4][48][49];
    __shared__ __align__(16) bf16 attn_s[48 * 72];

    const int bh = blockIdx.x;
    const int b = bh >> 3, h = bh & 7;
    const int t = threadIdx.x;
    const int wave = t >> 6, lane = t & 63;
    const int quad = lane >> 4, r = lane & 15;
    const int tensor = lane >> 5;
    const int n_local = lane & 31;

    const size_t qkv_base = (size_t)b * N_ * 1152;
    const int toff = 384 + tensor * 384 + h * 48;

    f32x4 acc[3][3] = {};
    bf16* kT = &stage[wave][0];
    bf16* vT = &stage[wave][1936];
    bf16* myT = &stage[wave][tensor * 1936];

    for (int c = wave; c < 25; c += 4) {
        int n0 = c * 32;
        bf16 rowbuf[48];
        if (n0 + n_local < N_) {
            const uint4* src = (const uint4*)(qkvb + qkv_base + (size_t)(n0 + n_local) * 1152 + toff);
            #pragma unroll
            for (int i = 0; i < 6; i++) *(uint4*)(&rowbuf[i * 8]) = src[i];
        } else {
            #pragma unroll
            for (int i = 0; i < 48; i++) rowbuf[i] = (bf16)0.f;
        }
        #pragma unroll
        for (int d = 0; d < 48; d++) myT[d * 40 + n_local] = rowbuf[d];
        bf16x8 af[3], bfv[3];
        #pragma unroll
        for (int i = 0; i < 3; i++) af[i]  = *(const bf16x8*)(&kT[(i * 16 + r) * 40 + quad * 8]);
        #pragma unroll
        for (int j = 0; j < 3; j++) bfv[j] = *(const bf16x8*)(&vT[(j * 16 + r) * 40 + quad * 8]);
        #pragma unroll
        for (int i = 0; i < 3; i++)
            #pragma unroll
            for (int j = 0; j < 3; j++)
                acc[i][j] = __builtin_amdgcn_mfma_f32_16x16x32_bf16(af[i], bfv[j], acc[i][j], 0, 0, 0);
    }

    #pragma unroll
    for (int i = 0; i < 3; i++)
        #pragma unroll
        for (int j = 0; j < 3; j++)
            #pragma unroll
            for (int e = 0; e < 4; e++)
                Sred[wave][i * 16 + quad * 4 + e][j * 16 + r] = acc[i][j][e];
    __syncthreads();

    if (t < 48) {
        float row[48];
        float mx = -1e30f;
        #pragma unroll
        for (int e = 0; e < 48; e++) {
            float s = Sred[0][t][e] + Sred[1][t][e] + Sred[2][t][e] + Sred[3][t][e];
            s *= 0.14433756729740644f;
            row[e] = s;
            mx = fmaxf(mx, s);
        }
        float sum = 0.f;
        #pragma unroll
        for (int e = 0; e < 48; e++) { float ex = __expf(row[e] - mx); row[e] = ex; sum += ex; }
        float inv = 1.f / sum;
        #pragma unroll
        for (int e = 0; e < 48; e++) attn_s[t * 72 + e] = (bf16)(row[e] * inv);
        #pragma unroll
        for (int e = 48; e < 64; e++) attn_s[t * 72 + e] = (bf16)0.f;
    }
    __syncthreads();

    const bf16* qbase = qkvb + qkv_base + h * 48;
    for (int nt = wave; nt < 49; nt += 4) {
        int n0 = nt * 16;
        f32x4 oacc[3] = {};
        #pragma unroll
        for (int kc = 0; kc < 2; kc++) {
            bf16x8 bq = *(const bf16x8*)(qbase + (size_t)(n0 + r) * 1152 + kc * 32 + quad * 8);
            #pragma unroll
            for (int i = 0; i < 3; i++) {
                bf16x8 aa = *(const bf16x8*)(&attn_s[(i * 16 + r) * 72 + kc * 32 + quad * 8]);
                oacc[i] = __builtin_amdgcn_mfma_f32_16x16x32_bf16(aa, bq, oacc[i], 0, 0, 0);
            }
        }
        #pragma unroll
        for (int i = 0; i < 3; i++) {
            bf16x4 ov;
            #pragma unroll
            for (int e = 0; e < 4; e++) ov[e] = (bf16)oacc[i][e];
            *(bf16x4*)(outp + (size_t)(b * N_ + n0 + r) * 384 + h * 48 + i * 16 + quad * 4) = ov;
        }
    }
}

// ---------------- launch ----------------
extern "C" void kernel_launch(void* const* d_in, const int* in_sizes, int n_in,
                              void* d_out, int out_size, void* d_ws, size_t ws_size,
                              hipStream_t stream) {
    const float* x      = (const float*)d_in[0];
    const float* cpe0_w = (const float*)d_in[3];
    const float* cpe0_b = (const float*)d_in[4];
    const float* cpe1_w = (const float*)d_in[5];
    const float* cpe1_b = (const float*)d_in[6];
    const float* n1g    = (const float*)d_in[7];
    const float* n1b    = (const float*)d_in[8];
    const float* qkv_w  = (const float*)d_in[9];
    const float* proj_w = (const float*)d_in[10];
    const float* proj_b = (const float*)d_in[11];
    const float* n2g    = (const float*)d_in[12];
    const float* n2b    = (const float*)d_in[13];
    const float* fc1_w  = (const float*)d_in[14];
    const float* fc1_b  = (const float*)d_in[15];
    const float* fc2_w  = (const float*)d_in[16];
    const float* fc2_b  = (const float*)d_in[17];

    char* ws = (char*)d_ws;
    size_t off = 0;
    bf16* cur    = (bf16*)(ws + off); off += (size_t)M_ * C_ * 2;
    bf16* qkvb   = (bf16*)(ws + off);
    float* x3    = (float*)qkvb;
    off += (size_t)M_ * 1152 * 2;
    bf16* hbuf   = (bf16*)(ws + off); off += (size_t)M_ * HID_ * 2;
    bf16* qkv_wb  = (bf16*)(ws + off); off += (size_t)1152 * 384 * 2;
    bf16* proj_wb = (bf16*)(ws + off); off += (size_t)384 * 384 * 2;
    bf16* fc1_wb  = (bf16*)(ws + off); off += (size_t)HID_ * 384 * 2;
    bf16* fc2_wb  = (bf16*)(ws + off); off += (size_t)384 * HID_ * 2;
    float* wt0    = (float*)(ws + off); off += (size_t)C_ * 9 * 4;
    float* wt1    = (float*)(ws + off); off += (size_t)C_ * 9 * 4;
    float* out = (float*)d_out;   // doubles as x1/x2 trunk buffer

    const int na = 442368, nb = 147456, nc = 589824, nd = 589824;
    const int ntot = na + nb + nc + nd + C_ * 9;
    prep_kernel<<<(ntot + 255) / 256, 256, 0, stream>>>(
        qkv_w, na, proj_w, nb, fc1_w, nc, fc2_w, nd, qkv_wb,
        cpe0_w, cpe1_w, wt0, wt1);

    // CPE0 + LN1: x -> out (x1, fp32) and cur (bf16)
    cpe_ln_kernel<<<M_ / 4, 256, 0, stream>>>(x, wt0, cpe0_b, out, n1g, n1b, cur);
    // qkv: cur @ qkv_w^T -> qkvb  (M x 1152, K=384)
    gemm_kernel<false, false, false, true><<<dim3(1152 / 128, M_ / 128), 256, 0, stream>>>(
        cur, qkv_wb, nullptr, nullptr, qkvb, M_, 1152, 384);
    // fused channel attention -> cur
    attn_fused_kernel<<<256, 256, 0, stream>>>(qkvb, cur);
    // proj + bias + residual -> out (fp32)
    gemm_kernel<true, false, true, false><<<dim3(384 / 128, M_ / 128), 256, 0, stream>>>(
        cur, proj_wb, proj_b, out, out, M_, 384, 384);
    // CPE1 + LN2: out (x2) -> x3 (fp32) and cur (bf16)
    cpe_ln_kernel<<<M_ / 4, 256, 0, stream>>>(out, wt1, cpe1_b, x3, n2g, n2b, cur);
    // fc1 + bias + gelu -> hbuf (bf16), M x 1536, K=384
    gemm_kernel<true, true, false, true><<<dim3(HID_ / 128, M_ / 128), 256, 0, stream>>>(
        cur, fc1_wb, fc1_b, nullptr, hbuf, M_, HID_, 384);
    // fc2 + bias + residual x3 -> d_out (fp32), M x 384, K=1536
    gemm_kernel<true, false, true, false><<<dim3(384 / 128, M_ / 128), 256, 0, stream>>>(
        hbuf, fc2_wb, fc2_b, x3, out, M_, 384, HID_);
}

// Round 8
// 380.521 us; speedup vs baseline: 1.0276x; 1.0276x over previous
//
#include <hip/hip_runtime.h>
#include <hip/hip_bf16.h>
#include <math.h>
#include <stdint.h>

#define B_     32
#define HH_    28
#define WW_    28
#define N_     784
#define C_     384
#define M_     25088      // B_*N_
#define HEADS_ 8
#define HD_    48
#define HID_   1536

typedef __bf16 bf16;
typedef __attribute__((ext_vector_type(8))) __bf16 bf16x8;
typedef __attribute__((ext_vector_type(4))) __bf16 bf16x4;
typedef __attribute__((ext_vector_type(4))) float f32x4;

// async global->LDS, 16B per lane; LDS dest = wave-uniform base + lane*16
__device__ __forceinline__ void gload_lds16(const void* g, void* l) {
    __builtin_amdgcn_global_load_lds(
        (const __attribute__((address_space(1))) unsigned int*)g,
        (__attribute__((address_space(3))) unsigned int*)(uintptr_t)l,
        16, 0, 0);
}

// fast GELU: v*sigmoid(2u), u = 0.79788456(v+0.044715v^3); validated R8-R14:
// absmax identical (0.03125) to erff baseline under bf16 rounding.
__device__ __forceinline__ float gelu_f(float v) {
    float u = 0.7978845608028654f * v * (1.f + 0.044715f * v * v);
    return __fdividef(v, 1.f + __expf(-2.f * u));
}

// ------- weights fp32 -> bf16 (4 tensors) + CPE weight transpose, one launch -------
__global__ void prep_kernel(const float* __restrict__ a, int na,
                            const float* __restrict__ b, int nb,
                            const float* __restrict__ c, int nc,
                            const float* __restrict__ d, int nd,
                            bf16* __restrict__ out,
                            const float* __restrict__ w0, const float* __restrict__ w1,
                            float* __restrict__ wt0, float* __restrict__ wt1) {
    int i = blockIdx.x * 256 + threadIdx.x;
    const int tot = na + nb + nc + nd;
    if (i < tot) {
        int j = i;
        const float* src;
        if (j < na) src = a + j;
        else { j -= na;
            if (j < nb) src = b + j;
            else { j -= nb;
                if (j < nc) src = c + j;
                else { j -= nc; src = d + j; } } }
        out[i] = (bf16)(*src);
    } else {
        int k = i - tot;                 // 0..C_*9-1
        if (k < C_ * 9) {
            int cc = k / 9, tt = k - cc * 9;
            wt0[tt * C_ + cc] = w0[k];
            wt1[tt * C_ + cc] = w1[k];
        }
    }
}

// ------- depthwise 3x3 conv + bias + residual, fused LayerNorm -> bf16 -------
// ONE WAVE PER ROW: lane l owns channels {l, l+64, ..., l+320}. LN reduction is a
// pure __shfl_xor butterfly — zero barriers, zero LDS. Border branch is
// wave-uniform (py/px per-row). Interior: 48 independent coalesced dword loads
// in flight. XCD-chunk swizzle: block f -> rows (f%8)*3136 + (f>>3)*4, so each
// XCD works on 4 whole images -> vertical 3x3 re-reads hit its own L2.
__global__ __launch_bounds__(256)
void cpe_ln_kernel(const float* __restrict__ x, const float* __restrict__ wt,
                   const float* __restrict__ bias, float* __restrict__ y,
                   const float* __restrict__ g, const float* __restrict__ beta,
                   bf16* __restrict__ lnout) {
    const int wave = threadIdx.x >> 6, lane = threadIdx.x & 63;
    const int f = blockIdx.x;
    const int row = (f & 7) * 3136 + (f >> 3) * 4 + wave;   // bijective over M_
    const int b = row / N_;
    const int n = row - b * N_;
    const int py = n / WW_, px = n - py * WW_;

    float acc[6], ctr[6];
    const float* xrow = x + (size_t)row * C_ + lane;
    #pragma unroll
    for (int j = 0; j < 6; j++) {
        acc[j] = bias[lane + j * 64];
        ctr[j] = xrow[j * 64];
    }

    if (py >= 1 && py <= 26 && px >= 1 && px <= 26) {
        // interior: 8 taps loaded unconditionally (center reuses ctr)
        const float* p = x + (size_t)(row - WW_ - 1) * C_ + lane;
        float v[9][6];
        #pragma unroll
        for (int t = 0; t < 9; t++) {
            if (t == 4) continue;
            const float* pt = p + ((t / 3) * WW_ + (t % 3)) * C_;
            #pragma unroll
            for (int j = 0; j < 6; j++) v[t][j] = pt[j * 64];
        }
        #pragma unroll
        for (int t = 0; t < 9; t++) {
            #pragma unroll
            for (int j = 0; j < 6; j++) {
                float xv = (t == 4) ? ctr[j] : v[t][j];
                acc[j] += wt[t * C_ + lane + j * 64] * xv;
            }
        }
    } else {
        #pragma unroll
        for (int t = 0; t < 9; t++) {
            int yy = py + t / 3 - 1, xx = px + t % 3 - 1;
            if (yy < 0 || yy >= HH_ || xx < 0 || xx >= WW_) continue;
            const float* pt = x + (size_t)(b * N_ + yy * WW_ + xx) * C_ + lane;
            #pragma unroll
            for (int j = 0; j < 6; j++)
                acc[j] += wt[t * C_ + lane + j * 64] * pt[j * 64];
        }
    }
    #pragma unroll
    for (int j = 0; j < 6; j++) acc[j] += ctr[j];

    float* yrow = y + (size_t)row * C_ + lane;
    #pragma unroll
    for (int j = 0; j < 6; j++) yrow[j * 64] = acc[j];

    // ---- LN: wave-wide butterfly, no barriers ----
    float s = 0.f;
    #pragma unroll
    for (int j = 0; j < 6; j++) s += acc[j];
    #pragma unroll
    for (int off = 1; off < 64; off <<= 1) s += __shfl_xor(s, off, 64);
    float mean = s * (1.f / C_);
    float d[6], vs = 0.f;
    #pragma unroll
    for (int j = 0; j < 6; j++) { d[j] = acc[j] - mean; vs += d[j] * d[j]; }
    #pragma unroll
    for (int off = 1; off < 64; off <<= 1) vs += __shfl_xor(vs, off, 64);
    float rstd = rsqrtf(vs * (1.f / C_) + 1e-5f);
    bf16* lrow = lnout + (size_t)row * C_ + lane;
    #pragma unroll
    for (int j = 0; j < 6; j++) {
        int c = lane + j * 64;
        lrow[j * 64] = (bf16)(d[j] * rstd * g[c] + beta[c]);
    }
}

// -------- bf16 MFMA GEMM: R13 ring-3 + bijective XCD-chunk swizzle (T1) --------
// R15: R13's GEMM (verified best, 61.5us fc1) with ONE change: work-sequence
// re-chunking so each XCD keeps its operand window in its private 4MB L2.
// Theory: fc1 stages 462MB (12x A-panels + 196x B) in 61.5us = 7.5 TB/s — above
// HBM, at the L3 service rate; MfmaUtil/VALU/HBM all low -> staging-BW-bound.
// Default dispatch round-robins consecutive blocks over 8 XCDs, so the 8 m-blocks
// sharing an A-window sit on 8 DIFFERENT XCDs -> every L2 thrashes all panels.
// Fix (m204 bijective): hw XCD = f&7 gets contiguous chunk of the seq; an XCD's
// ~96 resident blocks then span one m-group (8 A-panels, 786KB) x all n
// (B <= 1.2MB) ~= 2MB -> L2-resident staging at ~60B/cyc/CU vs L3 ~25.
// Keeps: ring-3/vmcnt(4) (R14 proved ring-2 worse), gelu_f, XOR-swizzle pair,
// scalar epilogue, VGPR 68.
template<bool BIAS, bool GELU, bool RESID, bool OUTBF>
__global__ __launch_bounds__(256)
void gemm_kernel(const bf16* __restrict__ A, const bf16* __restrict__ Wt,
                 const float* __restrict__ bias, const float* __restrict__ resid,
                 void* __restrict__ outp, int M, int N, int K) {
    __shared__ __align__(16) bf16 As[3 * 4096];
    __shared__ __align__(16) bf16 Bs[3 * 4096];

    const int nbn = gridDim.x, nbm = gridDim.y;
    const int nwg = nbn * nbm;
    const int fhw = blockIdx.y * nbn + blockIdx.x;      // hw linear id; runs on XCD fhw&7
    // bijective XCD-chunk (m204): XCD x owns seq [start(x), start(x)+cnt(x))
    const int xcd = fhw & 7, loc = fhw >> 3;
    const int q = nwg >> 3, rr = nwg & 7;
    const int seq = (xcd < rr ? xcd * (q + 1) : rr * (q + 1) + (xcd - rr) * q) + loc;
    // group-of-8 m-swizzle on the sequence (A-window reuse within a chunk)
    const int grp = seq / (8 * nbn);
    const int rem = seq - grp * 8 * nbn;
    const int rows = min(8, nbm - grp * 8);
    const int bm = (grp * 8 + rem % rows) * 128;
    const int bn = (rem / rows) * 128;

    const int t = threadIdx.x;
    const int wave = t >> 6, lane = t & 63;
    const int wm = (wave & 1) * 64, wn = (wave >> 1) * 64;
    const int quad = lane >> 4, r = lane & 15;

    const int ldrow = lane >> 2;
    // inverse swizzle on the global source: col-slot ^= row[2:1] (row_local = lane>>2)
    const int ldcol = ((lane & 3) ^ ((lane >> 3) & 3)) * 8;
    const bf16* ga0 = A  + (size_t)(bm + wave * 32 + ldrow) * K + ldcol;
    const bf16* ga1 = ga0 + (size_t)16 * K;
    const bf16* gb0 = Wt + (size_t)(bn + wave * 32 + ldrow) * K + ldcol;
    const bf16* gb1 = gb0 + (size_t)16 * K;
    const int lbase = wave * 32 * 32;

    f32x4 acc[4][4] = {};

    gload_lds16(ga0, &As[lbase]);
    gload_lds16(ga1, &As[lbase + 512]);
    gload_lds16(gb0, &Bs[lbase]);
    gload_lds16(gb1, &Bs[lbase + 512]);
    gload_lds16(ga0 + 32, &As[4096 + lbase]);
    gload_lds16(ga1 + 32, &As[4096 + lbase + 512]);
    gload_lds16(gb0 + 32, &Bs[4096 + lbase]);
    gload_lds16(gb1 + 32, &Bs[4096 + lbase + 512]);

    // read-side swizzle: col-quad ^= r[2:1] (row bits beyond r are multiples of 16)
    const int sq = (quad ^ ((r >> 1) & 3)) * 8;

    int buf = 0;
    int k0 = 0;
    for (; k0 < K - 32; k0 += 32) {
        asm volatile("s_waitcnt vmcnt(4)" ::: "memory");
        asm volatile("s_barrier" ::: "memory");
        if (k0 + 64 < K) {
            const int nb3 = (buf == 0 ? 2 : buf - 1) * 4096;   // (buf+2)%3
            gload_lds16(ga0 + k0 + 64, &As[nb3 + lbase]);
            gload_lds16(ga1 + k0 + 64, &As[nb3 + lbase + 512]);
            gload_lds16(gb0 + k0 + 64, &Bs[nb3 + lbase]);
            gload_lds16(gb1 + k0 + 64, &Bs[nb3 + lbase + 512]);
        }
        const bf16* as = &As[buf * 4096];
        const bf16* bs = &Bs[buf * 4096];
        bf16x8 af[4], bfr[4];
        #pragma unroll
        for (int i = 0; i < 4; i++)
            af[i] = *(const bf16x8*)(&as[(wm + i * 16 + r) * 32 + sq]);
        #pragma unroll
        for (int j = 0; j < 4; j++)
            bfr[j] = *(const bf16x8*)(&bs[(wn + j * 16 + r) * 32 + sq]);
        #pragma unroll
        for (int i = 0; i < 4; i++)
            #pragma unroll
            for (int j = 0; j < 4; j++)
                acc[i][j] = __builtin_amdgcn_mfma_f32_16x16x32_bf16(af[i], bfr[j], acc[i][j], 0, 0, 0);
        buf = (buf == 2) ? 0 : buf + 1;
    }
    {
        asm volatile("s_waitcnt vmcnt(0)" ::: "memory");
        asm volatile("s_barrier" ::: "memory");
        const bf16* as = &As[buf * 4096];
        const bf16* bs = &Bs[buf * 4096];
        bf16x8 af[4], bfr[4];
        #pragma unroll
        for (int i = 0; i < 4; i++)
            af[i] = *(const bf16x8*)(&as[(wm + i * 16 + r) * 32 + sq]);
        #pragma unroll
        for (int j = 0; j < 4; j++)
            bfr[j] = *(const bf16x8*)(&bs[(wn + j * 16 + r) * 32 + sq]);
        #pragma unroll
        for (int i = 0; i < 4; i++)
            #pragma unroll
            for (int j = 0; j < 4; j++)
                acc[i][j] = __builtin_amdgcn_mfma_f32_16x16x32_bf16(af[i], bfr[j], acc[i][j], 0, 0, 0);
    }

    #pragma unroll
    for (int i = 0; i < 4; i++) {
        #pragma unroll
        for (int j = 0; j < 4; j++) {
            int n = bn + wn + j * 16 + r;
            float bv = BIAS ? bias[n] : 0.f;
            #pragma unroll
            for (int e = 0; e < 4; e++) {
                int m = bm + wm + i * 16 + quad * 4 + e;
                float val = acc[i][j][e] + bv;
                if (GELU) val = gelu_f(val);
                if (RESID) val += resid[(size_t)m * N + n];
                if (OUTBF) ((bf16*)outp)[(size_t)m * N + n] = (bf16)val;
                else       ((float*)outp)[(size_t)m * N + n] = val;
            }
        }
    }
}

// ---------------- fused channel attention (scores + softmax + apply), MFMA ----------
__global__ __launch_bounds__(256)
void attn_fused_kernel(const bf16* __restrict__ qkvb, bf16* __restrict__ outp) {
    __shared__ __align__(16) bf16 stage[4][3872];
    __shared__ float Sred[4][48][49];
    __shared__ __align__(16) bf16 attn_s[48 * 72];

    const int bh = blockIdx.x;
    const int b = bh >> 3, h = bh & 7;
    const int t = threadIdx.x;
    const int wave = t >> 6, lane = t & 63;
    const int quad = lane >> 4, r = lane & 15;
    const int tensor = lane >> 5;
    const int n_local = lane & 31;

    const size_t qkv_base = (size_t)b * N_ * 1152;
    const int toff = 384 + tensor * 384 + h * 48;

    f32x4 acc[3][3] = {};
    bf16* kT = &stage[wave][0];
    bf16* vT = &stage[wave][1936];
    bf16* myT = &stage[wave][tensor * 1936];

    for (int c = wave; c < 25; c += 4) {
        int n0 = c * 32;
        bf16 rowbuf[48];
        if (n0 + n_local < N_) {
            const uint4* src = (const uint4*)(qkvb + qkv_base + (size_t)(n0 + n_local) * 1152 + toff);
            #pragma unroll
            for (int i = 0; i < 6; i++) *(uint4*)(&rowbuf[i * 8]) = src[i];
        } else {
            #pragma unroll
            for (int i = 0; i < 48; i++) rowbuf[i] = (bf16)0.f;
        }
        #pragma unroll
        for (int d = 0; d < 48; d++) myT[d * 40 + n_local] = rowbuf[d];
        bf16x8 af[3], bfv[3];
        #pragma unroll
        for (int i = 0; i < 3; i++) af[i]  = *(const bf16x8*)(&kT[(i * 16 + r) * 40 + quad * 8]);
        #pragma unroll
        for (int j = 0; j < 3; j++) bfv[j] = *(const bf16x8*)(&vT[(j * 16 + r) * 40 + quad * 8]);
        #pragma unroll
        for (int i = 0; i < 3; i++)
            #pragma unroll
            for (int j = 0; j < 3; j++)
                acc[i][j] = __builtin_amdgcn_mfma_f32_16x16x32_bf16(af[i], bfv[j], acc[i][j], 0, 0, 0);
    }

    #pragma unroll
    for (int i = 0; i < 3; i++)
        #pragma unroll
        for (int j = 0; j < 3; j++)
            #pragma unroll
            for (int e = 0; e < 4; e++)
                Sred[wave][i * 16 + quad * 4 + e][j * 16 + r] = acc[i][j][e];
    __syncthreads();

    if (t < 48) {
        float row[48];
        float mx = -1e30f;
        #pragma unroll
        for (int e = 0; e < 48; e++) {
            float s = Sred[0][t][e] + Sred[1][t][e] + Sred[2][t][e] + Sred[3][t][e];
            s *= 0.14433756729740644f;
            row[e] = s;
            mx = fmaxf(mx, s);
        }
        float sum = 0.f;
        #pragma unroll
        for (int e = 0; e < 48; e++) { float ex = __expf(row[e] - mx); row[e] = ex; sum += ex; }
        float inv = 1.f / sum;
        #pragma unroll
        for (int e = 0; e < 48; e++) attn_s[t * 72 + e] = (bf16)(row[e] * inv);
        #pragma unroll
        for (int e = 48; e < 64; e++) attn_s[t * 72 + e] = (bf16)0.f;
    }
    __syncthreads();

    const bf16* qbase = qkvb + qkv_base + h * 48;
    for (int nt = wave; nt < 49; nt += 4) {
        int n0 = nt * 16;
        f32x4 oacc[3] = {};
        #pragma unroll
        for (int kc = 0; kc < 2; kc++) {
            bf16x8 bq = *(const bf16x8*)(qbase + (size_t)(n0 + r) * 1152 + kc * 32 + quad * 8);
            #pragma unroll
            for (int i = 0; i < 3; i++) {
                bf16x8 aa = *(const bf16x8*)(&attn_s[(i * 16 + r) * 72 + kc * 32 + quad * 8]);
                oacc[i] = __builtin_amdgcn_mfma_f32_16x16x32_bf16(aa, bq, oacc[i], 0, 0, 0);
            }
        }
        #pragma unroll
        for (int i = 0; i < 3; i++) {
            bf16x4 ov;
            #pragma unroll
            for (int e = 0; e < 4; e++) ov[e] = (bf16)oacc[i][e];
            *(bf16x4*)(outp + (size_t)(b * N_ + n0 + r) * 384 + h * 48 + i * 16 + quad * 4) = ov;
        }
    }
}

// ---------------- launch ----------------
extern "C" void kernel_launch(void* const* d_in, const int* in_sizes, int n_in,
                              void* d_out, int out_size, void* d_ws, size_t ws_size,
                              hipStream_t stream) {
    const float* x      = (const float*)d_in[0];
    const float* cpe0_w = (const float*)d_in[3];
    const float* cpe0_b = (const float*)d_in[4];
    const float* cpe1_w = (const float*)d_in[5];
    const float* cpe1_b = (const float*)d_in[6];
    const float* n1g    = (const float*)d_in[7];
    const float* n1b    = (const float*)d_in[8];
    const float* qkv_w  = (const float*)d_in[9];
    const float* proj_w = (const float*)d_in[10];
    const float* proj_b = (const float*)d_in[11];
    const float* n2g    = (const float*)d_in[12];
    const float* n2b    = (const float*)d_in[13];
    const float* fc1_w  = (const float*)d_in[14];
    const float* fc1_b  = (const float*)d_in[15];
    const float* fc2_w  = (const float*)d_in[16];
    const float* fc2_b  = (const float*)d_in[17];

    char* ws = (char*)d_ws;
    size_t off = 0;
    bf16* cur    = (bf16*)(ws + off); off += (size_t)M_ * C_ * 2;
    bf16* qkvb   = (bf16*)(ws + off);
    float* x3    = (float*)qkvb;
    off += (size_t)M_ * 1152 * 2;
    bf16* hbuf   = (bf16*)(ws + off); off += (size_t)M_ * HID_ * 2;
    bf16* qkv_wb  = (bf16*)(ws + off); off += (size_t)1152 * 384 * 2;
    bf16* proj_wb = (bf16*)(ws + off); off += (size_t)384 * 384 * 2;
    bf16* fc1_wb  = (bf16*)(ws + off); off += (size_t)HID_ * 384 * 2;
    bf16* fc2_wb  = (bf16*)(ws + off); off += (size_t)384 * HID_ * 2;
    float* wt0    = (float*)(ws + off); off += (size_t)C_ * 9 * 4;
    float* wt1    = (float*)(ws + off); off += (size_t)C_ * 9 * 4;
    float* out = (float*)d_out;   // doubles as x1/x2 trunk buffer

    const int na = 442368, nb = 147456, nc = 589824, nd = 589824;
    const int ntot = na + nb + nc + nd + C_ * 9;
    prep_kernel<<<(ntot + 255) / 256, 256, 0, stream>>>(
        qkv_w, na, proj_w, nb, fc1_w, nc, fc2_w, nd, qkv_wb,
        cpe0_w, cpe1_w, wt0, wt1);

    // CPE0 + LN1: x -> out (x1, fp32) and cur (bf16)
    cpe_ln_kernel<<<M_ / 4, 256, 0, stream>>>(x, wt0, cpe0_b, out, n1g, n1b, cur);
    // qkv: cur @ qkv_w^T -> qkvb  (M x 1152, K=384)
    gemm_kernel<false, false, false, true><<<dim3(1152 / 128, M_ / 128), 256, 0, stream>>>(
        cur, qkv_wb, nullptr, nullptr, qkvb, M_, 1152, 384);
    // fused channel attention -> cur
    attn_fused_kernel<<<256, 256, 0, stream>>>(qkvb, cur);
    // proj + bias + residual -> out (fp32)
    gemm_kernel<true, false, true, false><<<dim3(384 / 128, M_ / 128), 256, 0, stream>>>(
        cur, proj_wb, proj_b, out, out, M_, 384, 384);
    // CPE1 + LN2: out (x2) -> x3 (fp32) and cur (bf16)
    cpe_ln_kernel<<<M_ / 4, 256, 0, stream>>>(out, wt1, cpe1_b, x3, n2g, n2b, cur);
    // fc1 + bias + gelu -> hbuf (bf16), M x 1536, K=384
    gemm_kernel<true, true, false, true><<<dim3(HID_ / 128, M_ / 128), 256, 0, stream>>>(
        cur, fc1_wb, fc1_b, nullptr, hbuf, M_, HID_, 384);
    // fc2 + bias + residual x3 -> d_out (fp32), M x 384, K=1536
    gemm_kernel<true, false, true, false><<<dim3(384 / 128, M_ / 128), 256, 0, stream>>>(
        hbuf, fc2_wb, fc2_b, x3, out, M_, 384, HID_);
}

// Round 9
// 374.531 us; speedup vs baseline: 1.0441x; 1.0160x over previous
//
#include <hip/hip_runtime.h>
#include <hip/hip_bf16.h>
#include <math.h>
#include <stdint.h>

#define B_     32
#define HH_    28
#define WW_    28
#define N_     784
#define C_     384
#define M_     25088      // B_*N_
#define HEADS_ 8
#define HD_    48
#define HID_   1536

typedef __bf16 bf16;
typedef __attribute__((ext_vector_type(8))) __bf16 bf16x8;
typedef __attribute__((ext_vector_type(4))) __bf16 bf16x4;
typedef __attribute__((ext_vector_type(4))) float f32x4;

// async global->LDS, 16B per lane; LDS dest = wave-uniform base + lane*16
__device__ __forceinline__ void gload_lds16(const void* g, void* l) {
    __builtin_amdgcn_global_load_lds(
        (const __attribute__((address_space(1))) unsigned int*)g,
        (__attribute__((address_space(3))) unsigned int*)(uintptr_t)l,
        16, 0, 0);
}

// fast GELU: v*sigmoid(2u), u = 0.79788456(v+0.044715v^3); validated R8-R15:
// absmax identical (0.03125) to erff baseline under bf16 rounding.
__device__ __forceinline__ float gelu_f(float v) {
    float u = 0.7978845608028654f * v * (1.f + 0.044715f * v * v);
    return __fdividef(v, 1.f + __expf(-2.f * u));
}

// ---------------- weights fp32 -> bf16, all four in one launch ----------------
__global__ void convert4_kernel(const float* __restrict__ a, int na,
                                const float* __restrict__ b, int nb,
                                const float* __restrict__ c, int nc,
                                const float* __restrict__ d, int nd,
                                bf16* __restrict__ out) {
    int i = blockIdx.x * 256 + threadIdx.x;
    int j = i;
    const float* src;
    if (j < na) src = a + j;
    else { j -= na;
        if (j < nb) src = b + j;
        else { j -= nb;
            if (j < nc) src = c + j;
            else { j -= nc;
                if (j >= nd) return;
                src = d + j; } } }
    out[i] = (bf16)(*src);
}

// ---------------- CPE weight transpose: w[c][tap] -> wt[tap][c], both convs ---------
__global__ void wtrans_kernel(const float* __restrict__ w0, const float* __restrict__ w1,
                              float* __restrict__ wt0, float* __restrict__ wt1) {
    int i = blockIdx.x * 256 + threadIdx.x;     // 0..3455
    if (i >= C_ * 9) return;
    int c = i / 9, t = i - c * 9;
    wt0[t * C_ + c] = w0[i];
    wt1[t * C_ + c] = w1[i];
}

// ------- depthwise 3x3 conv + bias + residual, fused LayerNorm -> bf16 -------
// ONE WAVE PER ROW: lane l owns channels {l, l+64, ..., l+320}. LN reduction is a
// pure __shfl_xor butterfly — zero barriers, zero LDS. Border branch is
// wave-uniform (py/px per-row). Interior: 48 independent coalesced dword loads
// in flight. XCD-chunk swizzle: block f -> rows (f%8)*3136 + (f>>3)*4, so each
// XCD works on 4 whole images -> vertical 3x3 re-reads hit its own L2.
__global__ __launch_bounds__(256)
void cpe_ln_kernel(const float* __restrict__ x, const float* __restrict__ wt,
                   const float* __restrict__ bias, float* __restrict__ y,
                   const float* __restrict__ g, const float* __restrict__ beta,
                   bf16* __restrict__ lnout) {
    const int wave = threadIdx.x >> 6, lane = threadIdx.x & 63;
    const int f = blockIdx.x;
    const int row = (f & 7) * 3136 + (f >> 3) * 4 + wave;   // bijective over M_
    const int b = row / N_;
    const int n = row - b * N_;
    const int py = n / WW_, px = n - py * WW_;

    float acc[6], ctr[6];
    const float* xrow = x + (size_t)row * C_ + lane;
    #pragma unroll
    for (int j = 0; j < 6; j++) {
        acc[j] = bias[lane + j * 64];
        ctr[j] = xrow[j * 64];
    }

    if (py >= 1 && py <= 26 && px >= 1 && px <= 26) {
        // interior: 8 taps loaded unconditionally (center reuses ctr)
        const float* p = x + (size_t)(row - WW_ - 1) * C_ + lane;
        float v[9][6];
        #pragma unroll
        for (int t = 0; t < 9; t++) {
            if (t == 4) continue;
            const float* pt = p + ((t / 3) * WW_ + (t % 3)) * C_;
            #pragma unroll
            for (int j = 0; j < 6; j++) v[t][j] = pt[j * 64];
        }
        #pragma unroll
        for (int t = 0; t < 9; t++) {
            #pragma unroll
            for (int j = 0; j < 6; j++) {
                float xv = (t == 4) ? ctr[j] : v[t][j];
                acc[j] += wt[t * C_ + lane + j * 64] * xv;
            }
        }
    } else {
        #pragma unroll
        for (int t = 0; t < 9; t++) {
            int yy = py + t / 3 - 1, xx = px + t % 3 - 1;
            if (yy < 0 || yy >= HH_ || xx < 0 || xx >= WW_) continue;
            const float* pt = x + (size_t)(b * N_ + yy * WW_ + xx) * C_ + lane;
            #pragma unroll
            for (int j = 0; j < 6; j++)
                acc[j] += wt[t * C_ + lane + j * 64] * pt[j * 64];
        }
    }
    #pragma unroll
    for (int j = 0; j < 6; j++) acc[j] += ctr[j];

    float* yrow = y + (size_t)row * C_ + lane;
    #pragma unroll
    for (int j = 0; j < 6; j++) yrow[j * 64] = acc[j];

    // ---- LN: wave-wide butterfly, no barriers ----
    float s = 0.f;
    #pragma unroll
    for (int j = 0; j < 6; j++) s += acc[j];
    #pragma unroll
    for (int off = 1; off < 64; off <<= 1) s += __shfl_xor(s, off, 64);
    float mean = s * (1.f / C_);
    float d[6], vs = 0.f;
    #pragma unroll
    for (int j = 0; j < 6; j++) { d[j] = acc[j] - mean; vs += d[j] * d[j]; }
    #pragma unroll
    for (int off = 1; off < 64; off <<= 1) vs += __shfl_xor(vs, off, 64);
    float rstd = rsqrtf(vs * (1.f / C_) + 1e-5f);
    bf16* lrow = lnout + (size_t)row * C_ + lane;
    #pragma unroll
    for (int j = 0; j < 6; j++) {
        int c = lane + j * 64;
        lrow[j * 64] = (bf16)(d[j] * rstd * g[c] + beta[c]);
    }
}

// -------- bf16 MFMA GEMM: R13 exact — ring-3, gelu_f, XOR-swizzle pair --------
// Verified best: 372.98us total, fc1 61.5us, conflicts 0, VGPR 68.
// Nine structural variants (R7-R15) bracket this as the optimum of the
// 2-barrier family on these skinny-K shapes:
//   ring-2/-4 worse (occupancy/prefetch tradeoff两-sided), 256-wide tiles
//   neutral-to-worse, barrier-free -60%, phase-split -15%, XCD swizzle -2%
//   (FETCH rose 15.5->26.3MB: default round-robin already gives temporal
//   A-window locality; chunking stretched reuse distance).
template<bool BIAS, bool GELU, bool RESID, bool OUTBF>
__global__ __launch_bounds__(256)
void gemm_kernel(const bf16* __restrict__ A, const bf16* __restrict__ Wt,
                 const float* __restrict__ bias, const float* __restrict__ resid,
                 void* __restrict__ outp, int M, int N, int K) {
    __shared__ __align__(16) bf16 As[3 * 4096];
    __shared__ __align__(16) bf16 Bs[3 * 4096];

    const int nbn = gridDim.x, nbm = gridDim.y;
    const int f = blockIdx.y * nbn + blockIdx.x;
    const int grp = f / (8 * nbn);
    const int rem = f - grp * 8 * nbn;
    const int rows = min(8, nbm - grp * 8);
    const int bm = (grp * 8 + rem % rows) * 128;
    const int bn = (rem / rows) * 128;

    const int t = threadIdx.x;
    const int wave = t >> 6, lane = t & 63;
    const int wm = (wave & 1) * 64, wn = (wave >> 1) * 64;
    const int quad = lane >> 4, r = lane & 15;

    const int ldrow = lane >> 2;
    // inverse swizzle on the global source: col-slot ^= row[2:1] (row_local = lane>>2)
    const int ldcol = ((lane & 3) ^ ((lane >> 3) & 3)) * 8;
    const bf16* ga0 = A  + (size_t)(bm + wave * 32 + ldrow) * K + ldcol;
    const bf16* ga1 = ga0 + (size_t)16 * K;
    const bf16* gb0 = Wt + (size_t)(bn + wave * 32 + ldrow) * K + ldcol;
    const bf16* gb1 = gb0 + (size_t)16 * K;
    const int lbase = wave * 32 * 32;

    f32x4 acc[4][4] = {};

    gload_lds16(ga0, &As[lbase]);
    gload_lds16(ga1, &As[lbase + 512]);
    gload_lds16(gb0, &Bs[lbase]);
    gload_lds16(gb1, &Bs[lbase + 512]);
    gload_lds16(ga0 + 32, &As[4096 + lbase]);
    gload_lds16(ga1 + 32, &As[4096 + lbase + 512]);
    gload_lds16(gb0 + 32, &Bs[4096 + lbase]);
    gload_lds16(gb1 + 32, &Bs[4096 + lbase + 512]);

    // read-side swizzle: col-quad ^= r[2:1] (row bits beyond r are multiples of 16)
    const int sq = (quad ^ ((r >> 1) & 3)) * 8;

    int buf = 0;
    int k0 = 0;
    for (; k0 < K - 32; k0 += 32) {
        asm volatile("s_waitcnt vmcnt(4)" ::: "memory");
        asm volatile("s_barrier" ::: "memory");
        if (k0 + 64 < K) {
            const int nb3 = (buf == 0 ? 2 : buf - 1) * 4096;   // (buf+2)%3
            gload_lds16(ga0 + k0 + 64, &As[nb3 + lbase]);
            gload_lds16(ga1 + k0 + 64, &As[nb3 + lbase + 512]);
            gload_lds16(gb0 + k0 + 64, &Bs[nb3 + lbase]);
            gload_lds16(gb1 + k0 + 64, &Bs[nb3 + lbase + 512]);
        }
        const bf16* as = &As[buf * 4096];
        const bf16* bs = &Bs[buf * 4096];
        bf16x8 af[4], bfr[4];
        #pragma unroll
        for (int i = 0; i < 4; i++)
            af[i] = *(const bf16x8*)(&as[(wm + i * 16 + r) * 32 + sq]);
        #pragma unroll
        for (int j = 0; j < 4; j++)
            bfr[j] = *(const bf16x8*)(&bs[(wn + j * 16 + r) * 32 + sq]);
        #pragma unroll
        for (int i = 0; i < 4; i++)
            #pragma unroll
            for (int j = 0; j < 4; j++)
                acc[i][j] = __builtin_amdgcn_mfma_f32_16x16x32_bf16(af[i], bfr[j], acc[i][j], 0, 0, 0);
        buf = (buf == 2) ? 0 : buf + 1;
    }
    {
        asm volatile("s_waitcnt vmcnt(0)" ::: "memory");
        asm volatile("s_barrier" ::: "memory");
        const bf16* as = &As[buf * 4096];
        const bf16* bs = &Bs[buf * 4096];
        bf16x8 af[4], bfr[4];
        #pragma unroll
        for (int i = 0; i < 4; i++)
            af[i] = *(const bf16x8*)(&as[(wm + i * 16 + r) * 32 + sq]);
        #pragma unroll
        for (int j = 0; j < 4; j++)
            bfr[j] = *(const bf16x8*)(&bs[(wn + j * 16 + r) * 32 + sq]);
        #pragma unroll
        for (int i = 0; i < 4; i++)
            #pragma unroll
            for (int j = 0; j < 4; j++)
                acc[i][j] = __builtin_amdgcn_mfma_f32_16x16x32_bf16(af[i], bfr[j], acc[i][j], 0, 0, 0);
    }

    #pragma unroll
    for (int i = 0; i < 4; i++) {
        #pragma unroll
        for (int j = 0; j < 4; j++) {
            int n = bn + wn + j * 16 + r;
            float bv = BIAS ? bias[n] : 0.f;
            #pragma unroll
            for (int e = 0; e < 4; e++) {
                int m = bm + wm + i * 16 + quad * 4 + e;
                float val = acc[i][j][e] + bv;
                if (GELU) val = gelu_f(val);
                if (RESID) val += resid[(size_t)m * N + n];
                if (OUTBF) ((bf16*)outp)[(size_t)m * N + n] = (bf16)val;
                else       ((float*)outp)[(size_t)m * N + n] = val;
            }
        }
    }
}

// ---------------- fused channel attention (scores + softmax + apply), MFMA ----------
__global__ __launch_bounds__(256)
void attn_fused_kernel(const bf16* __restrict__ qkvb, bf16* __restrict__ outp) {
    __shared__ __align__(16) bf16 stage[4][3872];
    __shared__ float Sred[4][48][49];
    __shared__ __align__(16) bf16 attn_s[48 * 72];

    const int bh = blockIdx.x;
    const int b = bh >> 3, h = bh & 7;
    const int t = threadIdx.x;
    const int wave = t >> 6, lane = t & 63;
    const int quad = lane >> 4, r = lane & 15;
    const int tensor = lane >> 5;
    const int n_local = lane & 31;

    const size_t qkv_base = (size_t)b * N_ * 1152;
    const int toff = 384 + tensor * 384 + h * 48;

    f32x4 acc[3][3] = {};
    bf16* kT = &stage[wave][0];
    bf16* vT = &stage[wave][1936];
    bf16* myT = &stage[wave][tensor * 1936];

    for (int c = wave; c < 25; c += 4) {
        int n0 = c * 32;
        bf16 rowbuf[48];
        if (n0 + n_local < N_) {
            const uint4* src = (const uint4*)(qkvb + qkv_base + (size_t)(n0 + n_local) * 1152 + toff);
            #pragma unroll
            for (int i = 0; i < 6; i++) *(uint4*)(&rowbuf[i * 8]) = src[i];
        } else {
            #pragma unroll
            for (int i = 0; i < 48; i++) rowbuf[i] = (bf16)0.f;
        }
        #pragma unroll
        for (int d = 0; d < 48; d++) myT[d * 40 + n_local] = rowbuf[d];
        bf16x8 af[3], bfv[3];
        #pragma unroll
        for (int i = 0; i < 3; i++) af[i]  = *(const bf16x8*)(&kT[(i * 16 + r) * 40 + quad * 8]);
        #pragma unroll
        for (int j = 0; j < 3; j++) bfv[j] = *(const bf16x8*)(&vT[(j * 16 + r) * 40 + quad * 8]);
        #pragma unroll
        for (int i = 0; i < 3; i++)
            #pragma unroll
            for (int j = 0; j < 3; j++)
                acc[i][j] = __builtin_amdgcn_mfma_f32_16x16x32_bf16(af[i], bfv[j], acc[i][j], 0, 0, 0);
    }

    #pragma unroll
    for (int i = 0; i < 3; i++)
        #pragma unroll
        for (int j = 0; j < 3; j++)
            #pragma unroll
            for (int e = 0; e < 4; e++)
                Sred[wave][i * 16 + quad * 4 + e][j * 16 + r] = acc[i][j][e];
    __syncthreads();

    if (t < 48) {
        float row[48];
        float mx = -1e30f;
        #pragma unroll
        for (int e = 0; e < 48; e++) {
            float s = Sred[0][t][e] + Sred[1][t][e] + Sred[2][t][e] + Sred[3][t][e];
            s *= 0.14433756729740644f;
            row[e] = s;
            mx = fmaxf(mx, s);
        }
        float sum = 0.f;
        #pragma unroll
        for (int e = 0; e < 48; e++) { float ex = __expf(row[e] - mx); row[e] = ex; sum += ex; }
        float inv = 1.f / sum;
        #pragma unroll
        for (int e = 0; e < 48; e++) attn_s[t * 72 + e] = (bf16)(row[e] * inv);
        #pragma unroll
        for (int e = 48; e < 64; e++) attn_s[t * 72 + e] = (bf16)0.f;
    }
    __syncthreads();

    const bf16* qbase = qkvb + qkv_base + h * 48;
    for (int nt = wave; nt < 49; nt += 4) {
        int n0 = nt * 16;
        f32x4 oacc[3] = {};
        #pragma unroll
        for (int kc = 0; kc < 2; kc++) {
            bf16x8 bq = *(const bf16x8*)(qbase + (size_t)(n0 + r) * 1152 + kc * 32 + quad * 8);
            #pragma unroll
            for (int i = 0; i < 3; i++) {
                bf16x8 aa = *(const bf16x8*)(&attn_s[(i * 16 + r) * 72 + kc * 32 + quad * 8]);
                oacc[i] = __builtin_amdgcn_mfma_f32_16x16x32_bf16(aa, bq, oacc[i], 0, 0, 0);
            }
        }
        #pragma unroll
        for (int i = 0; i < 3; i++) {
            bf16x4 ov;
            #pragma unroll
            for (int e = 0; e < 4; e++) ov[e] = (bf16)oacc[i][e];
            *(bf16x4*)(outp + (size_t)(b * N_ + n0 + r) * 384 + h * 48 + i * 16 + quad * 4) = ov;
        }
    }
}

// ---------------- launch ----------------
extern "C" void kernel_launch(void* const* d_in, const int* in_sizes, int n_in,
                              void* d_out, int out_size, void* d_ws, size_t ws_size,
                              hipStream_t stream) {
    const float* x      = (const float*)d_in[0];
    const float* cpe0_w = (const float*)d_in[3];
    const float* cpe0_b = (const float*)d_in[4];
    const float* cpe1_w = (const float*)d_in[5];
    const float* cpe1_b = (const float*)d_in[6];
    const float* n1g    = (const float*)d_in[7];
    const float* n1b    = (const float*)d_in[8];
    const float* qkv_w  = (const float*)d_in[9];
    const float* proj_w = (const float*)d_in[10];
    const float* proj_b = (const float*)d_in[11];
    const float* n2g    = (const float*)d_in[12];
    const float* n2b    = (const float*)d_in[13];
    const float* fc1_w  = (const float*)d_in[14];
    const float* fc1_b  = (const float*)d_in[15];
    const float* fc2_w  = (const float*)d_in[16];
    const float* fc2_b  = (const float*)d_in[17];

    char* ws = (char*)d_ws;
    size_t off = 0;
    bf16* cur    = (bf16*)(ws + off); off += (size_t)M_ * C_ * 2;
    bf16* qkvb   = (bf16*)(ws + off);
    float* x3    = (float*)qkvb;
    off += (size_t)M_ * 1152 * 2;
    bf16* hbuf   = (bf16*)(ws + off); off += (size_t)M_ * HID_ * 2;
    bf16* qkv_wb  = (bf16*)(ws + off); off += (size_t)1152 * 384 * 2;
    bf16* proj_wb = (bf16*)(ws + off); off += (size_t)384 * 384 * 2;
    bf16* fc1_wb  = (bf16*)(ws + off); off += (size_t)HID_ * 384 * 2;
    bf16* fc2_wb  = (bf16*)(ws + off); off += (size_t)384 * HID_ * 2;
    float* wt0    = (float*)(ws + off); off += (size_t)C_ * 9 * 4;
    float* wt1    = (float*)(ws + off); off += (size_t)C_ * 9 * 4;
    float* out = (float*)d_out;   // doubles as x1/x2 trunk buffer

    const int na = 442368, nb = 147456, nc = 589824, nd = 589824;
    convert4_kernel<<<(na + nb + nc + nd + 255) / 256, 256, 0, stream>>>(
        qkv_w, na, proj_w, nb, fc1_w, nc, fc2_w, nd, qkv_wb);
    wtrans_kernel<<<(C_ * 9 + 255) / 256, 256, 0, stream>>>(cpe0_w, cpe1_w, wt0, wt1);

    // CPE0 + LN1: x -> out (x1, fp32) and cur (bf16)
    cpe_ln_kernel<<<M_ / 4, 256, 0, stream>>>(x, wt0, cpe0_b, out, n1g, n1b, cur);
    // qkv: cur @ qkv_w^T -> qkvb  (M x 1152, K=384)
    gemm_kernel<false, false, false, true><<<dim3(1152 / 128, M_ / 128), 256, 0, stream>>>(
        cur, qkv_wb, nullptr, nullptr, qkvb, M_, 1152, 384);
    // fused channel attention -> cur
    attn_fused_kernel<<<256, 256, 0, stream>>>(qkvb, cur);
    // proj + bias + residual -> out (fp32)
    gemm_kernel<true, false, true, false><<<dim3(384 / 128, M_ / 128), 256, 0, stream>>>(
        cur, proj_wb, proj_b, out, out, M_, 384, 384);
    // CPE1 + LN2: out (x2) -> x3 (fp32) and cur (bf16)
    cpe_ln_kernel<<<M_ / 4, 256, 0, stream>>>(out, wt1, cpe1_b, x3, n2g, n2b, cur);
    // fc1 + bias + gelu -> hbuf (bf16), M x 1536, K=384
    gemm_kernel<true, true, false, true><<<dim3(HID_ / 128, M_ / 128), 256, 0, stream>>>(
        cur, fc1_wb, fc1_b, nullptr, hbuf, M_, HID_, 384);
    // fc2 + bias + residual x3 -> d_out (fp32), M x 384, K=1536
    gemm_kernel<true, false, true, false><<<dim3(384 / 128, M_ / 128), 256, 0, stream>>>(
        hbuf, fc2_wb, fc2_b, x3, out, M_, 384, HID_);
}